// Round 8
// baseline (238.351 us; speedup 1.0000x reference)
//
#include <hip/hip_runtime.h>
#include <hip/hip_fp16.h>

// GCN forward: 3x (MFMA GEMM + normalized adjacency aggregate + ReLU) + mean-pool + linear + log_softmax
// N=50000, E=800000, F=H=128, C=10, G=512
// Round 8: fused kernel re-tiled to 128-thr/32-row blocks (2x blocks/CU), gather
// unrolled 8-deep (2x loads in flight), and layer-2 agg fused with mean-pool
// (LDS per-graph partials + atomic flush; kills HB write + pool read).

#define FEAT 128
#define NCLASS 10
#define NB_MAX 512  // max dst buckets (n <= 65536 here: 391)
#define GSPAN 8     // graphs tracked in LDS per agg_pool block

typedef _Float16 h8 __attribute__((ext_vector_type(8)));
typedef float f4 __attribute__((ext_vector_type(4)));

// LDS tile swizzle: row stride 256B; XOR row&7 into byte bits 4..6 so that
// phase-2 column reads (16 rows @ same col) spread across 8 16B slots (2-way = free).
__device__ inline int swz(int row, int cbyte) { return row * 256 + (cbyte ^ ((row & 7) << 4)); }

// 8-deep gather-accumulate of one node's in-edges (16-lane group, h8/lane).
// acc a0..a3 are float[8] partials; csr range [s,e).
__device__ inline void gather8(const h8* __restrict__ Hs, const int* __restrict__ csr,
                               int s, int e, int lig, float* a0, float* a1, float* a2,
                               float* a3) {
  for (int k = s; k < e; k += 8) {
    int i0 = csr[k];
    int i1 = (k + 1 < e) ? csr[k + 1] : -1;
    int i2 = (k + 2 < e) ? csr[k + 2] : -1;
    int i3 = (k + 3 < e) ? csr[k + 3] : -1;
    int i4 = (k + 4 < e) ? csr[k + 4] : -1;
    int i5 = (k + 5 < e) ? csr[k + 5] : -1;
    int i6 = (k + 6 < e) ? csr[k + 6] : -1;
    int i7 = (k + 7 < e) ? csr[k + 7] : -1;
    h8 v0 = Hs[(size_t)i0 * 16 + lig];
    h8 v1 = Hs[(size_t)max(i1, 0) * 16 + lig];
    h8 v2 = Hs[(size_t)max(i2, 0) * 16 + lig];
    h8 v3 = Hs[(size_t)max(i3, 0) * 16 + lig];
    h8 v4 = Hs[(size_t)max(i4, 0) * 16 + lig];
    h8 v5 = Hs[(size_t)max(i5, 0) * 16 + lig];
    h8 v6 = Hs[(size_t)max(i6, 0) * 16 + lig];
    h8 v7 = Hs[(size_t)max(i7, 0) * 16 + lig];
#pragma unroll
    for (int j = 0; j < 8; ++j) a0[j] += (float)v0[j];
    if (i1 >= 0) {
#pragma unroll
      for (int j = 0; j < 8; ++j) a1[j] += (float)v1[j];
    }
    if (i2 >= 0) {
#pragma unroll
      for (int j = 0; j < 8; ++j) a2[j] += (float)v2[j];
    }
    if (i3 >= 0) {
#pragma unroll
      for (int j = 0; j < 8; ++j) a3[j] += (float)v3[j];
    }
    if (i4 >= 0) {
#pragma unroll
      for (int j = 0; j < 8; ++j) a0[j] += (float)v4[j];
    }
    if (i5 >= 0) {
#pragma unroll
      for (int j = 0; j < 8; ++j) a1[j] += (float)v5[j];
    }
    if (i6 >= 0) {
#pragma unroll
      for (int j = 0; j < 8; ++j) a2[j] += (float)v6[j];
    }
    if (i7 >= 0) {
#pragma unroll
      for (int j = 0; j < 8; ++j) a3[j] += (float)v7[j];
    }
  }
}

// ---- pass 0: bucket histogram of dst>>7 (blocks 0..hb-1) + Wt convert (rest) ----
__global__ void __launch_bounds__(256) hist_wt_kernel(const int* __restrict__ ei,
                                                      int* __restrict__ bhist,
                                                      int ne, int nb, int epb, int hb,
                                                      const float* __restrict__ W0,
                                                      const float* __restrict__ W1,
                                                      const float* __restrict__ W2,
                                                      _Float16* __restrict__ Wt) {
  int t = threadIdx.x;
  if (blockIdx.x >= hb) {
    // Wt[l][n][k] = W_l[k][n]
    int i = (blockIdx.x - hb) * 256 + t;
    if (i < 3 * FEAT * FEAT) {
      int l = i / (FEAT * FEAT);
      int r = i - l * (FEAT * FEAT);
      int nn = r >> 7, kk = r & 127;
      const float* W = (l == 0) ? W0 : (l == 1) ? W1 : W2;
      Wt[i] = (_Float16)W[kk * FEAT + nn];
    }
    return;
  }
  __shared__ int lh[NB_MAX];
  for (int i = t; i < nb; i += 256) lh[i] = 0;
  __syncthreads();
  int r0 = blockIdx.x * epb;
  int r1 = min(r0 + epb, ne);
  for (int k = r0 + t; k < r1; k += 256) atomicAdd(&lh[ei[ne + k] >> 7], 1);
  __syncthreads();
  for (int i = t; i < nb; i += 256)
    if (lh[i]) atomicAdd(&bhist[i], lh[i]);
}

// ---- exclusive scan of bucket counts -> bstart (kept) and bcur (consumed) ----
__global__ void __launch_bounds__(512) bscan_kernel(const int* __restrict__ bhist,
                                                    int* __restrict__ bstart,
                                                    int* __restrict__ bcur,
                                                    int* __restrict__ off,
                                                    int nb, int n, int ne) {
  __shared__ int sh[512];
  int t = threadIdx.x;
  int v = (t < nb) ? bhist[t] : 0;
  sh[t] = v;
  __syncthreads();
  int x = v;
  for (int d = 1; d < 512; d <<= 1) {
    int y = (t >= d) ? sh[t - d] : 0;
    __syncthreads();
    x += y;
    sh[t] = x;
    __syncthreads();
  }
  if (t < nb) {
    bstart[t] = x - v;
    bcur[t] = x - v;
  }
  if (t == 0) {
    bstart[nb] = ne;
    off[n] = ne;
  }
}

// ---- pass 1: scatter packed (dst&127,src) into dst-buckets ----
__global__ void __launch_bounds__(256) scatter_kernel(const int* __restrict__ ei,
                                                      int* __restrict__ bcur,
                                                      unsigned* __restrict__ buf,
                                                      int ne, int nb, int epb) {
  __shared__ int lh[NB_MAX], lbs[NB_MAX];
  int t = threadIdx.x;
  for (int i = t; i < nb; i += 256) lh[i] = 0;
  __syncthreads();
  int r0 = blockIdx.x * epb;
  int r1 = min(r0 + epb, ne);
  for (int k = r0 + t; k < r1; k += 256) atomicAdd(&lh[ei[ne + k] >> 7], 1);
  __syncthreads();
  for (int i = t; i < nb; i += 256) {
    int c = lh[i];
    lbs[i] = c ? atomicAdd(&bcur[i], c) : 0;
    lh[i] = 0;  // reuse as local cursor
  }
  __syncthreads();
  for (int k = r0 + t; k < r1; k += 256) {
    int src = ei[k];
    int dst = ei[ne + k];
    int b = dst >> 7;
    int p = lbs[b] + atomicAdd(&lh[b], 1);
    buf[p] = (unsigned)src | ((unsigned)(dst & 127) << 25);
  }
}

// ---- pass 2: one block per bucket: LDS count -> scan -> dis/off/csr ----
__global__ void __launch_bounds__(256) bucket_build_kernel(const unsigned* __restrict__ buf,
                                                           const int* __restrict__ bstart,
                                                           int* __restrict__ off,
                                                           int* __restrict__ csr,
                                                           float* __restrict__ dis, int n) {
  __shared__ int cnt[128], cur[128], sh[128];
  int b = blockIdx.x, t = threadIdx.x;
  int e0 = bstart[b], e1 = bstart[b + 1];
  if (t < 128) cnt[t] = 0;
  __syncthreads();
  for (int k = e0 + t; k < e1; k += 256) atomicAdd(&cnt[buf[k] >> 25], 1);
  __syncthreads();
  int v = (t < 128) ? cnt[t] : 0;
  if (t < 128) sh[t] = v;
  __syncthreads();
  int x = v;
  for (int d = 1; d < 128; d <<= 1) {
    int y = (t < 128 && t >= d) ? sh[t - d] : 0;
    __syncthreads();
    if (t < 128) {
      x += y;
      sh[t] = x;
    }
    __syncthreads();
  }
  if (t < 128) {
    int node = (b << 7) + t;
    cur[t] = x - v;
    if (node < n) {
      off[node] = e0 + x - v;
      dis[node] = rsqrtf((float)(v + 1));
    }
  }
  __syncthreads();
  for (int k = e0 + t; k < e1; k += 256) {
    unsigned u = buf[k];
    int d = u >> 25;
    int p = atomicAdd(&cur[d], 1);
    csr[e0 + p] = (int)(u & 0x1FFFFFFu);
  }
}

// Hs(f16) = (X @ W) * dis[row] via v_mfma_f32_16x16x32_f16 (layer 0, f32 input)
__global__ void __launch_bounds__(256) gemm_mfma_kernel(const float* __restrict__ Xf,
                                                        const _Float16* __restrict__ Wt,
                                                        const float* __restrict__ dis,
                                                        _Float16* __restrict__ Hs, int n) {
  __shared__ _Float16 st[64 * FEAT];  // 16 KB epilogue staging
  int tid = threadIdx.x;
  int w = tid >> 6, lane = tid & 63;
  int l15 = lane & 15, hi = lane >> 4;

  int rowA = blockIdx.x * 64 + w * 16 + l15;
  int rA = min(rowA, n - 1);

  f4 acc[8];
#pragma unroll
  for (int nb = 0; nb < 8; ++nb) acc[nb] = (f4)(0.f);

#pragma unroll
  for (int kk = 0; kk < FEAT; kk += 32) {
    int ko = kk + hi * 8;
    h8 a;
    float4 x0 = *(const float4*)&Xf[(size_t)rA * FEAT + ko];
    float4 x1 = *(const float4*)&Xf[(size_t)rA * FEAT + ko + 4];
    a[0] = (_Float16)x0.x; a[1] = (_Float16)x0.y; a[2] = (_Float16)x0.z; a[3] = (_Float16)x0.w;
    a[4] = (_Float16)x1.x; a[5] = (_Float16)x1.y; a[6] = (_Float16)x1.z; a[7] = (_Float16)x1.w;
#pragma unroll
    for (int nb = 0; nb < 8; ++nb) {
      h8 bfr = *(const h8*)&Wt[(nb * 16 + l15) * FEAT + ko];
      acc[nb] = __builtin_amdgcn_mfma_f32_16x16x32_f16(a, bfr, acc[nb], 0, 0, 0);
    }
  }

  float dv[4];
#pragma unroll
  for (int r = 0; r < 4; ++r) {
    int grow = blockIdx.x * 64 + w * 16 + hi * 4 + r;
    dv[r] = dis[min(grow, n - 1)];
  }
#pragma unroll
  for (int nb = 0; nb < 8; ++nb)
#pragma unroll
    for (int r = 0; r < 4; ++r)
      st[(w * 16 + hi * 4 + r) * FEAT + nb * 16 + l15] = (_Float16)(acc[nb][r] * dv[r]);
  __syncthreads();

  int rowbase = blockIdx.x * 64;
#pragma unroll
  for (int i = tid; i < 64 * FEAT / 8; i += 256) {
    int row = rowbase + (i >> 4);
    if (row < n)
      *(uint4*)&Hs[(size_t)row * FEAT + (i & 15) * 8] =
          *(const uint4*)&st[(i >> 4) * FEAT + (i & 15) * 8];
  }
}

// Fused: A = relu(dis*agg(Hs_in) + b_prev) per node (32 nodes -> swizzled LDS
// tile), then Hs_out = (A @ W) * dis via MFMA. 128 thr / 2 waves / 32 rows.
__global__ void __launch_bounds__(128) fused_kernel(const h8* __restrict__ Hs_in,
                                                    const int* __restrict__ csr,
                                                    const int* __restrict__ off,
                                                    const float* __restrict__ dis,
                                                    const float* __restrict__ bias,
                                                    const _Float16* __restrict__ Wt,
                                                    _Float16* __restrict__ Hs_out, int n) {
  __shared__ char xsb[32 * 256];  // 8 KB: A-tile, then reused as epilogue staging
  int tid = threadIdx.x;
  int g16 = tid >> 4, lig = tid & 15;  // 8 groups x 16 lanes
  int row0 = blockIdx.x * 32;

  float4 b0 = ((const float4*)bias)[lig * 2];
  float4 b1 = ((const float4*)bias)[lig * 2 + 1];
  float bb[8] = {b0.x, b0.y, b0.z, b0.w, b1.x, b1.y, b1.z, b1.w};

  // ---- phase 1: aggregate 4 nodes per group (8 loads in flight) ----
  for (int m = 0; m < 4; ++m) {
    int ar = g16 * 4 + m;
    int nd = min(row0 + ar, n - 1);
    int s = off[nd], e = off[nd + 1];
    float a0[8], a1[8], a2[8], a3[8];
    h8 v = Hs_in[(size_t)nd * 16 + lig];  // self-loop term
#pragma unroll
    for (int j = 0; j < 8; ++j) {
      a0[j] = (float)v[j];
      a1[j] = a2[j] = a3[j] = 0.f;
    }
    gather8(Hs_in, csr, s, e, lig, a0, a1, a2, a3);
    float d = dis[nd];
    h8 o;
#pragma unroll
    for (int j = 0; j < 8; ++j) {
      float sum = a0[j] + a1[j] + a2[j] + a3[j];
      o[j] = (_Float16)fmaxf(fmaf(d, sum, bb[j]), 0.f);
    }
    *(h8*)(xsb + swz(ar, lig * 16)) = o;
  }
  __syncthreads();

  // ---- phase 2: MFMA from LDS A-tile ----
  int w = tid >> 6, lane = tid & 63;
  int l15 = lane & 15, hi = lane >> 4;
  f4 acc[8];
#pragma unroll
  for (int nb = 0; nb < 8; ++nb) acc[nb] = (f4)(0.f);
#pragma unroll
  for (int kk = 0; kk < FEAT; kk += 32) {
    int ko = kk + hi * 8;
    h8 a = *(const h8*)(xsb + swz(w * 16 + l15, ko * 2));
#pragma unroll
    for (int nb = 0; nb < 8; ++nb) {
      h8 bfr = *(const h8*)&Wt[(nb * 16 + l15) * FEAT + ko];
      acc[nb] = __builtin_amdgcn_mfma_f32_16x16x32_f16(a, bfr, acc[nb], 0, 0, 0);
    }
  }

  float dv[4];
#pragma unroll
  for (int r = 0; r < 4; ++r) {
    int grow = row0 + w * 16 + hi * 4 + r;
    dv[r] = dis[min(grow, n - 1)];
  }
  __syncthreads();  // all A-reads done before reusing xsb as staging
#pragma unroll
  for (int nb = 0; nb < 8; ++nb)
#pragma unroll
    for (int r = 0; r < 4; ++r) {
      int srow = w * 16 + hi * 4 + r;
      *(_Float16*)(xsb + swz(srow, (nb * 16 + l15) * 2)) = (_Float16)(acc[nb][r] * dv[r]);
    }
  __syncthreads();
#pragma unroll
  for (int i = tid; i < 32 * FEAT / 8; i += 128) {
    int row = row0 + (i >> 4);
    if (row < n)
      *(uint4*)&Hs_out[(size_t)row * FEAT + (i & 15) * 8] =
          *(const uint4*)(xsb + swz(i >> 4, (i & 15) * 16));
  }
}

// Layer-2 agg fused with mean-pool partials: out row = relu(dis*agg+b) is
// accumulated into pooled[batch[node]] via LDS per-graph partials (batch sorted
// -> a 64-node block spans ~1-2 graphs).
__global__ void __launch_bounds__(256) agg_pool_kernel(const h8* __restrict__ Hs,
                                                       const int* __restrict__ csr,
                                                       const int* __restrict__ off,
                                                       const float* __restrict__ dis,
                                                       const float* __restrict__ bias,
                                                       const int* __restrict__ batch,
                                                       float* __restrict__ pooled, int n) {
  __shared__ float sums[GSPAN][FEAT];  // 4 KB
  int tid = threadIdx.x;
  int g16 = tid >> 4, lig = tid & 15;  // 16 groups x 16 lanes
  int row0 = blockIdx.x * 64;
  int bmin = batch[min(row0, n - 1)];

  for (int i = tid; i < GSPAN * FEAT; i += 256) sums[i >> 7][i & 127] = 0.f;
  __syncthreads();

  float4 b0 = ((const float4*)bias)[lig * 2];
  float4 b1 = ((const float4*)bias)[lig * 2 + 1];
  float bb[8] = {b0.x, b0.y, b0.z, b0.w, b1.x, b1.y, b1.z, b1.w};

  for (int m = 0; m < 4; ++m) {
    int node = row0 + g16 * 4 + m;
    if (node >= n) break;
    int s = off[node], e = off[node + 1];
    float a0[8], a1[8], a2[8], a3[8];
    h8 v = Hs[(size_t)node * 16 + lig];  // self-loop term
#pragma unroll
    for (int j = 0; j < 8; ++j) {
      a0[j] = (float)v[j];
      a1[j] = a2[j] = a3[j] = 0.f;
    }
    gather8(Hs, csr, s, e, lig, a0, a1, a2, a3);
    float d = dis[node];
    int gl = batch[node] - bmin;
    if (gl < GSPAN) {
#pragma unroll
      for (int j = 0; j < 8; ++j) {
        float sum = a0[j] + a1[j] + a2[j] + a3[j];
        atomicAdd(&sums[gl][lig * 8 + j], fmaxf(fmaf(d, sum, bb[j]), 0.f));
      }
    } else {  // pathological span; essentially never
#pragma unroll
      for (int j = 0; j < 8; ++j) {
        float sum = a0[j] + a1[j] + a2[j] + a3[j];
        atomicAdd(&pooled[(size_t)batch[node] * FEAT + lig * 8 + j],
                  fmaxf(fmaf(d, sum, bb[j]), 0.f));
      }
    }
  }
  __syncthreads();

  int bmax = batch[min(row0 + 63, n - 1)];
  int span = min(bmax - bmin + 1, GSPAN);
  for (int i = tid; i < span * FEAT; i += 256) {
    float vv = sums[i >> 7][i & 127];
    if (vv != 0.f) atomicAdd(&pooled[(size_t)(bmin + (i >> 7)) * FEAT + (i & 127)], vv);
  }
}

// graph boundaries from sorted batch
__global__ void bounds_kernel(const int* __restrict__ batch, int* __restrict__ gstart,
                              int n, int g) {
  int i = blockIdx.x * 256 + threadIdx.x;
  if (i >= n) return;
  int bi = batch[i];
  int bp = (i == 0) ? -1 : batch[i - 1];
  for (int q = bp + 1; q <= bi; ++q) gstart[q] = i;
  if (i == n - 1) {
    for (int q = bi + 1; q <= g; ++q) gstart[q] = n;
  }
}

// per-graph: mean (pooled/cnt) + linear(128->10) + log_softmax
__global__ void __launch_bounds__(128) pool2_kernel(const float* __restrict__ pooled,
                                                    const int* __restrict__ gstart,
                                                    const float* __restrict__ lw,
                                                    const float* __restrict__ lb,
                                                    float* __restrict__ out) {
  int g = blockIdx.x;
  int t = threadIdx.x;
  float cnt = (float)(gstart[g + 1] - gstart[g]);
  float pv = pooled[(size_t)g * FEAT + t] / fmaxf(cnt, 1.f);
  __shared__ float lds[FEAT];
  __shared__ float logits[NCLASS];
  lds[t] = pv;
  __syncthreads();
  if (t < NCLASS) {
    float z = lb[t];
    for (int k = 0; k < FEAT; ++k) z += lds[k] * lw[k * NCLASS + t];
    logits[t] = z;
  }
  __syncthreads();
  if (t < NCLASS) {
    float m = logits[0];
#pragma unroll
    for (int c = 1; c < NCLASS; ++c) m = fmaxf(m, logits[c]);
    float ssum = 0.f;
#pragma unroll
    for (int c = 0; c < NCLASS; ++c) ssum += expf(logits[c] - m);
    out[(size_t)g * NCLASS + t] = logits[t] - m - logf(ssum);
  }
}

extern "C" void kernel_launch(void* const* d_in, const int* in_sizes, int n_in,
                              void* d_out, int out_size, void* d_ws, size_t ws_size,
                              hipStream_t stream) {
  const float* x = (const float*)d_in[0];
  const int* ei = (const int*)d_in[1];
  const int* batch = (const int*)d_in[2];
  const float* W0 = (const float*)d_in[3];
  const float* b0 = (const float*)d_in[4];
  const float* W1 = (const float*)d_in[5];
  const float* b1 = (const float*)d_in[6];
  const float* W2 = (const float*)d_in[7];
  const float* b2 = (const float*)d_in[8];
  const float* lw = (const float*)d_in[9];
  const float* lb = (const float*)d_in[10];

  int n = in_sizes[2];        // 50000 nodes
  int ne = in_sizes[1] / 2;   // 800000 edges
  int g = out_size / NCLASS;  // 512 graphs
  int nb = (n + 127) >> 7;    // dst buckets (391)
  int hblocks = 120;
  int epb = (ne + hblocks - 1) / hblocks;
  int wtblocks = (3 * FEAT * FEAT + 255) / 256;  // 192

  char* ws = (char*)d_ws;
  size_t p = 0;
  auto alloc = [&](size_t bytes) {
    size_t cur = p;
    p += (bytes + 255) & ~(size_t)255;
    return cur;
  };
  int* off = (int*)(ws + alloc((size_t)(n + 1) * 4));
  int* csr = (int*)(ws + alloc((size_t)ne * 4));
  int* bhist = (int*)(ws + alloc((size_t)NB_MAX * 4));
  int* bstart = (int*)(ws + alloc((size_t)(NB_MAX + 1) * 4));
  int* bcur = (int*)(ws + alloc((size_t)NB_MAX * 4));
  int* gstart = (int*)(ws + alloc((size_t)(g + 1) * 4));
  float* dis = (float*)(ws + alloc((size_t)n * 4));
  unsigned* buf = (unsigned*)(ws + alloc((size_t)ne * 4));
  _Float16* Wt = (_Float16*)(ws + alloc((size_t)3 * FEAT * FEAT * 2));
  float* pooled = (float*)(ws + alloc((size_t)g * FEAT * 4));
  _Float16* HA = (_Float16*)(ws + alloc((size_t)n * FEAT * 2));
  _Float16* HB = (_Float16*)(ws + alloc((size_t)n * FEAT * 2));

  hipMemsetAsync(bhist, 0, NB_MAX * 4, stream);
  hipMemsetAsync(pooled, 0, (size_t)g * FEAT * 4, stream);

  hist_wt_kernel<<<hblocks + wtblocks, 256, 0, stream>>>(ei, bhist, ne, nb, epb, hblocks,
                                                         W0, W1, W2, Wt);
  bscan_kernel<<<1, 512, 0, stream>>>(bhist, bstart, bcur, off, nb, n, ne);
  scatter_kernel<<<hblocks, 256, 0, stream>>>(ei, bcur, buf, ne, nb, epb);
  bucket_build_kernel<<<nb, 256, 0, stream>>>(buf, bstart, off, csr, dis, n);

  // layer 0: X(f32) @ W0 * dis -> HA
  gemm_mfma_kernel<<<(n + 63) / 64, 256, 0, stream>>>(x, Wt, dis, HA, n);
  // layer 0 agg + layer 1 gemm: HA -> HB
  fused_kernel<<<(n + 31) / 32, 128, 0, stream>>>((const h8*)HA, csr, off, dis, b0,
                                                  Wt + (size_t)1 * FEAT * FEAT, HB, n);
  // layer 1 agg + layer 2 gemm: HB -> HA
  fused_kernel<<<(n + 31) / 32, 128, 0, stream>>>((const h8*)HB, csr, off, dis, b1,
                                                  Wt + (size_t)2 * FEAT * FEAT, HA, n);
  // layer 2 agg + pooled partial sums
  agg_pool_kernel<<<(n + 63) / 64, 256, 0, stream>>>((const h8*)HA, csr, off, dis, b2,
                                                     batch, pooled, n);

  bounds_kernel<<<(n + 255) / 256, 256, 0, stream>>>(batch, gstart, n, g);
  pool2_kernel<<<g, 128, 0, stream>>>(pooled, gstart, lw, lb, (float*)d_out);
}

// Round 9
// 227.123 us; speedup vs baseline: 1.0494x; 1.0494x over previous
//
#include <hip/hip_runtime.h>
#include <hip/hip_fp16.h>

// GCN forward: 3x (MFMA GEMM + normalized adjacency aggregate + ReLU) + mean-pool + linear + log_softmax
// N=50000, E=800000, F=H=128, C=10, G=512
// Round 9: revert to round-7 structure (fused 256thr/64row, standalone agg+pool
// — the LDS-atomic agg_pool fusion regressed); single lever: phase-1 gather
// deepened to 8 loads in flight per 16-lane group (32/wave).

#define FEAT 128
#define NCLASS 10
#define NB_MAX 512  // max dst buckets (n <= 65536 here: 391)

typedef _Float16 h8 __attribute__((ext_vector_type(8)));
typedef float f4 __attribute__((ext_vector_type(4)));

// LDS tile swizzle: row stride 256B; XOR row&7 into byte bits 4..6 so that
// phase-2 column reads (16 rows @ same col) spread across 8 16B slots (2-way = free).
__device__ inline int swz(int row, int cbyte) { return row * 256 + (cbyte ^ ((row & 7) << 4)); }

// 8-deep gather-accumulate of one node's in-edges (16-lane group, h8/lane).
__device__ inline void gather8(const h8* __restrict__ Hs, const int* __restrict__ csr,
                               int s, int e, int lig, float* a0, float* a1, float* a2,
                               float* a3) {
  for (int k = s; k < e; k += 8) {
    int i0 = csr[k];
    int i1 = (k + 1 < e) ? csr[k + 1] : -1;
    int i2 = (k + 2 < e) ? csr[k + 2] : -1;
    int i3 = (k + 3 < e) ? csr[k + 3] : -1;
    int i4 = (k + 4 < e) ? csr[k + 4] : -1;
    int i5 = (k + 5 < e) ? csr[k + 5] : -1;
    int i6 = (k + 6 < e) ? csr[k + 6] : -1;
    int i7 = (k + 7 < e) ? csr[k + 7] : -1;
    h8 v0 = Hs[(size_t)i0 * 16 + lig];
    h8 v1 = Hs[(size_t)max(i1, 0) * 16 + lig];
    h8 v2 = Hs[(size_t)max(i2, 0) * 16 + lig];
    h8 v3 = Hs[(size_t)max(i3, 0) * 16 + lig];
    h8 v4 = Hs[(size_t)max(i4, 0) * 16 + lig];
    h8 v5 = Hs[(size_t)max(i5, 0) * 16 + lig];
    h8 v6 = Hs[(size_t)max(i6, 0) * 16 + lig];
    h8 v7 = Hs[(size_t)max(i7, 0) * 16 + lig];
#pragma unroll
    for (int j = 0; j < 8; ++j) a0[j] += (float)v0[j];
    if (i1 >= 0) {
#pragma unroll
      for (int j = 0; j < 8; ++j) a1[j] += (float)v1[j];
    }
    if (i2 >= 0) {
#pragma unroll
      for (int j = 0; j < 8; ++j) a2[j] += (float)v2[j];
    }
    if (i3 >= 0) {
#pragma unroll
      for (int j = 0; j < 8; ++j) a3[j] += (float)v3[j];
    }
    if (i4 >= 0) {
#pragma unroll
      for (int j = 0; j < 8; ++j) a0[j] += (float)v4[j];
    }
    if (i5 >= 0) {
#pragma unroll
      for (int j = 0; j < 8; ++j) a1[j] += (float)v5[j];
    }
    if (i6 >= 0) {
#pragma unroll
      for (int j = 0; j < 8; ++j) a2[j] += (float)v6[j];
    }
    if (i7 >= 0) {
#pragma unroll
      for (int j = 0; j < 8; ++j) a3[j] += (float)v7[j];
    }
  }
}

// ---- pass 0: bucket histogram of dst>>7 (blocks 0..hb-1) + Wt convert (rest) ----
__global__ void __launch_bounds__(256) hist_wt_kernel(const int* __restrict__ ei,
                                                      int* __restrict__ bhist,
                                                      int ne, int nb, int epb, int hb,
                                                      const float* __restrict__ W0,
                                                      const float* __restrict__ W1,
                                                      const float* __restrict__ W2,
                                                      _Float16* __restrict__ Wt) {
  int t = threadIdx.x;
  if (blockIdx.x >= hb) {
    // Wt[l][n][k] = W_l[k][n]
    int i = (blockIdx.x - hb) * 256 + t;
    if (i < 3 * FEAT * FEAT) {
      int l = i / (FEAT * FEAT);
      int r = i - l * (FEAT * FEAT);
      int nn = r >> 7, kk = r & 127;
      const float* W = (l == 0) ? W0 : (l == 1) ? W1 : W2;
      Wt[i] = (_Float16)W[kk * FEAT + nn];
    }
    return;
  }
  __shared__ int lh[NB_MAX];
  for (int i = t; i < nb; i += 256) lh[i] = 0;
  __syncthreads();
  int r0 = blockIdx.x * epb;
  int r1 = min(r0 + epb, ne);
  for (int k = r0 + t; k < r1; k += 256) atomicAdd(&lh[ei[ne + k] >> 7], 1);
  __syncthreads();
  for (int i = t; i < nb; i += 256)
    if (lh[i]) atomicAdd(&bhist[i], lh[i]);
}

// ---- exclusive scan of bucket counts -> bstart (kept) and bcur (consumed) ----
__global__ void __launch_bounds__(512) bscan_kernel(const int* __restrict__ bhist,
                                                    int* __restrict__ bstart,
                                                    int* __restrict__ bcur,
                                                    int* __restrict__ off,
                                                    int nb, int n, int ne) {
  __shared__ int sh[512];
  int t = threadIdx.x;
  int v = (t < nb) ? bhist[t] : 0;
  sh[t] = v;
  __syncthreads();
  int x = v;
  for (int d = 1; d < 512; d <<= 1) {
    int y = (t >= d) ? sh[t - d] : 0;
    __syncthreads();
    x += y;
    sh[t] = x;
    __syncthreads();
  }
  if (t < nb) {
    bstart[t] = x - v;
    bcur[t] = x - v;
  }
  if (t == 0) {
    bstart[nb] = ne;
    off[n] = ne;
  }
}

// ---- pass 1: scatter packed (dst&127,src) into dst-buckets ----
__global__ void __launch_bounds__(256) scatter_kernel(const int* __restrict__ ei,
                                                      int* __restrict__ bcur,
                                                      unsigned* __restrict__ buf,
                                                      int ne, int nb, int epb) {
  __shared__ int lh[NB_MAX], lbs[NB_MAX];
  int t = threadIdx.x;
  for (int i = t; i < nb; i += 256) lh[i] = 0;
  __syncthreads();
  int r0 = blockIdx.x * epb;
  int r1 = min(r0 + epb, ne);
  for (int k = r0 + t; k < r1; k += 256) atomicAdd(&lh[ei[ne + k] >> 7], 1);
  __syncthreads();
  for (int i = t; i < nb; i += 256) {
    int c = lh[i];
    lbs[i] = c ? atomicAdd(&bcur[i], c) : 0;
    lh[i] = 0;  // reuse as local cursor
  }
  __syncthreads();
  for (int k = r0 + t; k < r1; k += 256) {
    int src = ei[k];
    int dst = ei[ne + k];
    int b = dst >> 7;
    int p = lbs[b] + atomicAdd(&lh[b], 1);
    buf[p] = (unsigned)src | ((unsigned)(dst & 127) << 25);
  }
}

// ---- pass 2: one block per bucket: LDS count -> scan -> dis/off/csr ----
__global__ void __launch_bounds__(256) bucket_build_kernel(const unsigned* __restrict__ buf,
                                                           const int* __restrict__ bstart,
                                                           int* __restrict__ off,
                                                           int* __restrict__ csr,
                                                           float* __restrict__ dis, int n) {
  __shared__ int cnt[128], cur[128], sh[128];
  int b = blockIdx.x, t = threadIdx.x;
  int e0 = bstart[b], e1 = bstart[b + 1];
  if (t < 128) cnt[t] = 0;
  __syncthreads();
  for (int k = e0 + t; k < e1; k += 256) atomicAdd(&cnt[buf[k] >> 25], 1);
  __syncthreads();
  int v = (t < 128) ? cnt[t] : 0;
  if (t < 128) sh[t] = v;
  __syncthreads();
  int x = v;
  for (int d = 1; d < 128; d <<= 1) {
    int y = (t < 128 && t >= d) ? sh[t - d] : 0;
    __syncthreads();
    if (t < 128) {
      x += y;
      sh[t] = x;
    }
    __syncthreads();
  }
  if (t < 128) {
    int node = (b << 7) + t;
    cur[t] = x - v;
    if (node < n) {
      off[node] = e0 + x - v;
      dis[node] = rsqrtf((float)(v + 1));
    }
  }
  __syncthreads();
  for (int k = e0 + t; k < e1; k += 256) {
    unsigned u = buf[k];
    int d = u >> 25;
    int p = atomicAdd(&cur[d], 1);
    csr[e0 + p] = (int)(u & 0x1FFFFFFu);
  }
}

// Hs(f16) = (X @ W) * dis[row] via v_mfma_f32_16x16x32_f16 (layer 0, f32 input)
__global__ void __launch_bounds__(256) gemm_mfma_kernel(const float* __restrict__ Xf,
                                                        const _Float16* __restrict__ Wt,
                                                        const float* __restrict__ dis,
                                                        _Float16* __restrict__ Hs, int n) {
  __shared__ _Float16 st[64 * FEAT];  // 16 KB epilogue staging
  int tid = threadIdx.x;
  int w = tid >> 6, lane = tid & 63;
  int l15 = lane & 15, hi = lane >> 4;

  int rowA = blockIdx.x * 64 + w * 16 + l15;
  int rA = min(rowA, n - 1);

  f4 acc[8];
#pragma unroll
  for (int nb = 0; nb < 8; ++nb) acc[nb] = (f4)(0.f);

#pragma unroll
  for (int kk = 0; kk < FEAT; kk += 32) {
    int ko = kk + hi * 8;
    h8 a;
    float4 x0 = *(const float4*)&Xf[(size_t)rA * FEAT + ko];
    float4 x1 = *(const float4*)&Xf[(size_t)rA * FEAT + ko + 4];
    a[0] = (_Float16)x0.x; a[1] = (_Float16)x0.y; a[2] = (_Float16)x0.z; a[3] = (_Float16)x0.w;
    a[4] = (_Float16)x1.x; a[5] = (_Float16)x1.y; a[6] = (_Float16)x1.z; a[7] = (_Float16)x1.w;
#pragma unroll
    for (int nb = 0; nb < 8; ++nb) {
      h8 bfr = *(const h8*)&Wt[(nb * 16 + l15) * FEAT + ko];
      acc[nb] = __builtin_amdgcn_mfma_f32_16x16x32_f16(a, bfr, acc[nb], 0, 0, 0);
    }
  }

  float dv[4];
#pragma unroll
  for (int r = 0; r < 4; ++r) {
    int grow = blockIdx.x * 64 + w * 16 + hi * 4 + r;
    dv[r] = dis[min(grow, n - 1)];
  }
#pragma unroll
  for (int nb = 0; nb < 8; ++nb)
#pragma unroll
    for (int r = 0; r < 4; ++r)
      st[(w * 16 + hi * 4 + r) * FEAT + nb * 16 + l15] = (_Float16)(acc[nb][r] * dv[r]);
  __syncthreads();

  int rowbase = blockIdx.x * 64;
#pragma unroll
  for (int i = tid; i < 64 * FEAT / 8; i += 256) {
    int row = rowbase + (i >> 4);
    if (row < n)
      *(uint4*)&Hs[(size_t)row * FEAT + (i & 15) * 8] =
          *(const uint4*)&st[(i >> 4) * FEAT + (i & 15) * 8];
  }
}

// Fused: A = relu(dis*agg(Hs_in) + b_prev) per node (64 nodes -> swizzled LDS
// tile), then Hs_out = (A @ W) * dis via MFMA. 256 thr / 4 waves / 64 rows.
// Phase 1: 16-lane group per node, 8 gathers in flight per group (32/wave).
__global__ void __launch_bounds__(256) fused_kernel(const h8* __restrict__ Hs_in,
                                                    const int* __restrict__ csr,
                                                    const int* __restrict__ off,
                                                    const float* __restrict__ dis,
                                                    const float* __restrict__ bias,
                                                    const _Float16* __restrict__ Wt,
                                                    _Float16* __restrict__ Hs_out, int n) {
  __shared__ char xsb[64 * 256];  // 16 KB: A-tile, then reused as epilogue staging
  int tid = threadIdx.x;
  int w = tid >> 6, lane = tid & 63;
  int grp = lane >> 4, lig = lane & 15;
  int row0 = blockIdx.x * 64;
  int g16 = w * 4 + grp;  // 0..15: group id in block

  float4 b0 = ((const float4*)bias)[lig * 2];
  float4 b1 = ((const float4*)bias)[lig * 2 + 1];
  float bb[8] = {b0.x, b0.y, b0.z, b0.w, b1.x, b1.y, b1.z, b1.w};

  // ---- phase 1: aggregate 4 nodes per 16-lane group ----
  for (int m = 0; m < 4; ++m) {
    int ar = g16 * 4 + m;
    int nd = min(row0 + ar, n - 1);
    int s = off[nd], e = off[nd + 1];
    float a0[8], a1[8], a2[8], a3[8];
    h8 v = Hs_in[(size_t)nd * 16 + lig];  // self-loop term
#pragma unroll
    for (int j = 0; j < 8; ++j) {
      a0[j] = (float)v[j];
      a1[j] = a2[j] = a3[j] = 0.f;
    }
    gather8(Hs_in, csr, s, e, lig, a0, a1, a2, a3);
    float d = dis[nd];
    h8 o;
#pragma unroll
    for (int j = 0; j < 8; ++j) {
      float sum = a0[j] + a1[j] + a2[j] + a3[j];
      o[j] = (_Float16)fmaxf(fmaf(d, sum, bb[j]), 0.f);
    }
    *(h8*)(xsb + swz(ar, lig * 16)) = o;
  }
  __syncthreads();

  // ---- phase 2: MFMA from LDS A-tile ----
  int l15 = lane & 15, hi = lane >> 4;
  f4 acc[8];
#pragma unroll
  for (int nb = 0; nb < 8; ++nb) acc[nb] = (f4)(0.f);
#pragma unroll
  for (int kk = 0; kk < FEAT; kk += 32) {
    int ko = kk + hi * 8;
    h8 a = *(const h8*)(xsb + swz(w * 16 + l15, ko * 2));
#pragma unroll
    for (int nb = 0; nb < 8; ++nb) {
      h8 bfr = *(const h8*)&Wt[(nb * 16 + l15) * FEAT + ko];
      acc[nb] = __builtin_amdgcn_mfma_f32_16x16x32_f16(a, bfr, acc[nb], 0, 0, 0);
    }
  }

  float dv[4];
#pragma unroll
  for (int r = 0; r < 4; ++r) {
    int grow = row0 + w * 16 + hi * 4 + r;
    dv[r] = dis[min(grow, n - 1)];
  }
  __syncthreads();  // all A-reads done before reusing xsb as staging
#pragma unroll
  for (int nb = 0; nb < 8; ++nb)
#pragma unroll
    for (int r = 0; r < 4; ++r) {
      int srow = w * 16 + hi * 4 + r;
      *(_Float16*)(xsb + swz(srow, (nb * 16 + l15) * 2)) = (_Float16)(acc[nb][r] * dv[r]);
    }
  __syncthreads();
#pragma unroll
  for (int i = tid; i < 64 * FEAT / 8; i += 256) {
    int row = row0 + (i >> 4);
    if (row < n)
      *(uint4*)&Hs_out[(size_t)row * FEAT + (i & 15) * 8] =
          *(const uint4*)(xsb + swz(i >> 4, (i & 15) * 16));
  }
}

// out(f16) = relu(dis[i] * (Hs[i] + sum Hs[src]) + b) — standalone (layer 2)
__global__ void __launch_bounds__(256) agg_kernel(const h8* __restrict__ Hs,
                                                  const int* __restrict__ csr,
                                                  const int* __restrict__ off,
                                                  const float* __restrict__ dis,
                                                  const float* __restrict__ b,
                                                  h8* __restrict__ out, int n) {
  int wave = threadIdx.x >> 6;
  int lane = threadIdx.x & 63;
  int grp = lane >> 4, lig = lane & 15;
  int node = blockIdx.x * 4 + wave;
  if (node >= n) return;
  int s = off[node];
  int e = off[node + 1];

  float acc[8];
  if (grp == 0) {
    h8 v = Hs[(size_t)node * 16 + lig];  // self-loop term
#pragma unroll
    for (int j = 0; j < 8; ++j) acc[j] = (float)v[j];
  } else {
#pragma unroll
    for (int j = 0; j < 8; ++j) acc[j] = 0.f;
  }

  for (int k = s; k < e; k += 16) {
    int k0 = k + grp, k1 = k0 + 4, k2 = k0 + 8, k3 = k0 + 12;
    int i0 = (k0 < e) ? csr[k0] : -1;
    int i1 = (k1 < e) ? csr[k1] : -1;
    int i2 = (k2 < e) ? csr[k2] : -1;
    int i3 = (k3 < e) ? csr[k3] : -1;
    h8 v0 = Hs[(size_t)max(i0, 0) * 16 + lig];
    h8 v1 = Hs[(size_t)max(i1, 0) * 16 + lig];
    h8 v2 = Hs[(size_t)max(i2, 0) * 16 + lig];
    h8 v3 = Hs[(size_t)max(i3, 0) * 16 + lig];
    if (i0 >= 0) {
#pragma unroll
      for (int j = 0; j < 8; ++j) acc[j] += (float)v0[j];
    }
    if (i1 >= 0) {
#pragma unroll
      for (int j = 0; j < 8; ++j) acc[j] += (float)v1[j];
    }
    if (i2 >= 0) {
#pragma unroll
      for (int j = 0; j < 8; ++j) acc[j] += (float)v2[j];
    }
    if (i3 >= 0) {
#pragma unroll
      for (int j = 0; j < 8; ++j) acc[j] += (float)v3[j];
    }
  }

#pragma unroll
  for (int j = 0; j < 8; ++j) {
    acc[j] += __shfl_xor(acc[j], 16);
    acc[j] += __shfl_xor(acc[j], 32);
  }

  if (grp == 0) {
    float d = dis[node];
    float4 b0 = ((const float4*)b)[lig * 2];
    float4 b1 = ((const float4*)b)[lig * 2 + 1];
    h8 o;
    o[0] = (_Float16)fmaxf(fmaf(d, acc[0], b0.x), 0.f);
    o[1] = (_Float16)fmaxf(fmaf(d, acc[1], b0.y), 0.f);
    o[2] = (_Float16)fmaxf(fmaf(d, acc[2], b0.z), 0.f);
    o[3] = (_Float16)fmaxf(fmaf(d, acc[3], b0.w), 0.f);
    o[4] = (_Float16)fmaxf(fmaf(d, acc[4], b1.x), 0.f);
    o[5] = (_Float16)fmaxf(fmaf(d, acc[5], b1.y), 0.f);
    o[6] = (_Float16)fmaxf(fmaf(d, acc[6], b1.z), 0.f);
    o[7] = (_Float16)fmaxf(fmaf(d, acc[7], b1.w), 0.f);
    out[(size_t)node * 16 + lig] = o;
  }
}

// graph boundaries from sorted batch
__global__ void bounds_kernel(const int* __restrict__ batch, int* __restrict__ gstart,
                              int n, int g) {
  int i = blockIdx.x * 256 + threadIdx.x;
  if (i >= n) return;
  int bi = batch[i];
  int bp = (i == 0) ? -1 : batch[i - 1];
  for (int q = bp + 1; q <= bi; ++q) gstart[q] = i;
  if (i == n - 1) {
    for (int q = bi + 1; q <= g; ++q) gstart[q] = n;
  }
}

// mean-pool per graph (f16 input) + linear(128->10) + log_softmax
__global__ void __launch_bounds__(128) pool_kernel(const __half* __restrict__ h,
                                                   const int* __restrict__ gstart,
                                                   const float* __restrict__ lw,
                                                   const float* __restrict__ lb,
                                                   float* __restrict__ out) {
  int g = blockIdx.x;
  int t = threadIdx.x;
  int s = gstart[g];
  int e = gstart[g + 1];
  float a0 = 0.f, a1 = 0.f, a2 = 0.f, a3 = 0.f;
  int i = s;
  for (; i + 4 <= e; i += 4) {
    a0 += __half2float(h[(size_t)i * FEAT + t]);
    a1 += __half2float(h[(size_t)(i + 1) * FEAT + t]);
    a2 += __half2float(h[(size_t)(i + 2) * FEAT + t]);
    a3 += __half2float(h[(size_t)(i + 3) * FEAT + t]);
  }
  for (; i < e; ++i) a0 += __half2float(h[(size_t)i * FEAT + t]);
  float acc = a0 + a1 + a2 + a3;
  float cnt = (float)(e - s);
  float pooled = acc / fmaxf(cnt, 1.f);
  __shared__ float lds[FEAT];
  __shared__ float logits[NCLASS];
  lds[t] = pooled;
  __syncthreads();
  if (t < NCLASS) {
    float z = lb[t];
    for (int k = 0; k < FEAT; ++k) z += lds[k] * lw[k * NCLASS + t];
    logits[t] = z;
  }
  __syncthreads();
  if (t < NCLASS) {
    float m = logits[0];
#pragma unroll
    for (int c = 1; c < NCLASS; ++c) m = fmaxf(m, logits[c]);
    float ssum = 0.f;
#pragma unroll
    for (int c = 0; c < NCLASS; ++c) ssum += expf(logits[c] - m);
    out[(size_t)g * NCLASS + t] = logits[t] - m - logf(ssum);
  }
}

extern "C" void kernel_launch(void* const* d_in, const int* in_sizes, int n_in,
                              void* d_out, int out_size, void* d_ws, size_t ws_size,
                              hipStream_t stream) {
  const float* x = (const float*)d_in[0];
  const int* ei = (const int*)d_in[1];
  const int* batch = (const int*)d_in[2];
  const float* W0 = (const float*)d_in[3];
  const float* b0 = (const float*)d_in[4];
  const float* W1 = (const float*)d_in[5];
  const float* b1 = (const float*)d_in[6];
  const float* W2 = (const float*)d_in[7];
  const float* b2 = (const float*)d_in[8];
  const float* lw = (const float*)d_in[9];
  const float* lb = (const float*)d_in[10];

  int n = in_sizes[2];        // 50000 nodes
  int ne = in_sizes[1] / 2;   // 800000 edges
  int g = out_size / NCLASS;  // 512 graphs
  int nb = (n + 127) >> 7;    // dst buckets (391)
  int hblocks = 120;
  int epb = (ne + hblocks - 1) / hblocks;
  int wtblocks = (3 * FEAT * FEAT + 255) / 256;  // 192

  char* ws = (char*)d_ws;
  size_t p = 0;
  auto alloc = [&](size_t bytes) {
    size_t cur = p;
    p += (bytes + 255) & ~(size_t)255;
    return cur;
  };
  int* off = (int*)(ws + alloc((size_t)(n + 1) * 4));
  int* csr = (int*)(ws + alloc((size_t)ne * 4));
  int* bhist = (int*)(ws + alloc((size_t)NB_MAX * 4));
  int* bstart = (int*)(ws + alloc((size_t)(NB_MAX + 1) * 4));
  int* bcur = (int*)(ws + alloc((size_t)NB_MAX * 4));
  int* gstart = (int*)(ws + alloc((size_t)(g + 1) * 4));
  float* dis = (float*)(ws + alloc((size_t)n * 4));
  unsigned* buf = (unsigned*)(ws + alloc((size_t)ne * 4));
  _Float16* Wt = (_Float16*)(ws + alloc((size_t)3 * FEAT * FEAT * 2));
  _Float16* HA = (_Float16*)(ws + alloc((size_t)n * FEAT * 2));
  _Float16* HB = (_Float16*)(ws + alloc((size_t)n * FEAT * 2));

  hipMemsetAsync(bhist, 0, NB_MAX * 4, stream);

  hist_wt_kernel<<<hblocks + wtblocks, 256, 0, stream>>>(ei, bhist, ne, nb, epb, hblocks,
                                                         W0, W1, W2, Wt);
  bscan_kernel<<<1, 512, 0, stream>>>(bhist, bstart, bcur, off, nb, n, ne);
  scatter_kernel<<<hblocks, 256, 0, stream>>>(ei, bcur, buf, ne, nb, epb);
  bucket_build_kernel<<<nb, 256, 0, stream>>>(buf, bstart, off, csr, dis, n);

  int gblocks = (n + 63) / 64;
  // layer 0: X(f32) @ W0 * dis -> HA
  gemm_mfma_kernel<<<gblocks, 256, 0, stream>>>(x, Wt, dis, HA, n);
  // layer 0 agg + layer 1 gemm: HA -> HB
  fused_kernel<<<gblocks, 256, 0, stream>>>((const h8*)HA, csr, off, dis, b0,
                                            Wt + (size_t)1 * FEAT * FEAT, HB, n);
  // layer 1 agg + layer 2 gemm: HB -> HA
  fused_kernel<<<gblocks, 256, 0, stream>>>((const h8*)HB, csr, off, dis, b1,
                                            Wt + (size_t)2 * FEAT * FEAT, HA, n);
  // layer 2 agg: HA -> HB (pool input)
  agg_kernel<<<(n + 3) / 4, 256, 0, stream>>>((const h8*)HA, csr, off, dis, b2, (h8*)HB, n);

  bounds_kernel<<<(n + 255) / 256, 256, 0, stream>>>(batch, gstart, n, g);
  pool_kernel<<<g, 128, 0, stream>>>((const __half*)HB, gstart, lw, lb, (float*)d_out);
}

// Round 10
// 225.388 us; speedup vs baseline: 1.0575x; 1.0077x over previous
//
#include <hip/hip_runtime.h>
#include <hip/hip_fp16.h>

// GCN forward: 3x (MFMA GEMM + normalized adjacency aggregate + ReLU) + mean-pool + linear + log_softmax
// N=50000, E=800000, F=H=128, C=10, G=512
// Round 10: round-7 structure + BRANCHLESS padded gather. CSR segments padded to
// multiple of 8 with zero-row sentinel (index n); gather = int4-vectorized index
// load + 8 unconditional h8 loads in flight. agg rewritten to same group form.

#define FEAT 128
#define NCLASS 10
#define NB_MAX 512  // max dst buckets (n <= 65536 here: 391)

typedef _Float16 h8 __attribute__((ext_vector_type(8)));
typedef float f4 __attribute__((ext_vector_type(4)));

// LDS tile swizzle: row stride 256B; XOR row&7 into byte bits 4..6.
__device__ inline int swz(int row, int cbyte) { return row * 256 + (cbyte ^ ((row & 7) << 4)); }

// Branchless padded gather: [s, s+pad8(e-s)) with sentinel entries = n (zero row).
// 8 loads in flight, 2 accumulator chains. s is 8-aligned.
__device__ inline void gather_pad8(const h8* __restrict__ Hs, const int* __restrict__ csr,
                                   int s, int e, int lig, float* a0, float* a1) {
  int ep = s + ((e - s + 7) & ~7);
  for (int k = s; k < ep; k += 8) {
    int4 c0 = *(const int4*)&csr[k];
    int4 c1 = *(const int4*)&csr[k + 4];
    h8 v0 = Hs[(size_t)c0.x * 16 + lig];
    h8 v1 = Hs[(size_t)c0.y * 16 + lig];
    h8 v2 = Hs[(size_t)c0.z * 16 + lig];
    h8 v3 = Hs[(size_t)c0.w * 16 + lig];
    h8 v4 = Hs[(size_t)c1.x * 16 + lig];
    h8 v5 = Hs[(size_t)c1.y * 16 + lig];
    h8 v6 = Hs[(size_t)c1.z * 16 + lig];
    h8 v7 = Hs[(size_t)c1.w * 16 + lig];
#pragma unroll
    for (int j = 0; j < 8; ++j) a0[j] += (float)v0[j];
#pragma unroll
    for (int j = 0; j < 8; ++j) a1[j] += (float)v1[j];
#pragma unroll
    for (int j = 0; j < 8; ++j) a0[j] += (float)v2[j];
#pragma unroll
    for (int j = 0; j < 8; ++j) a1[j] += (float)v3[j];
#pragma unroll
    for (int j = 0; j < 8; ++j) a0[j] += (float)v4[j];
#pragma unroll
    for (int j = 0; j < 8; ++j) a1[j] += (float)v5[j];
#pragma unroll
    for (int j = 0; j < 8; ++j) a0[j] += (float)v6[j];
#pragma unroll
    for (int j = 0; j < 8; ++j) a1[j] += (float)v7[j];
  }
}

// ---- pass 0 combined: bucket histogram (blocks <hb) + Wt convert + bounds ----
__global__ void __launch_bounds__(256) prep_kernel(const int* __restrict__ ei,
                                                   int* __restrict__ bhist,
                                                   int ne, int nb, int epb, int hb,
                                                   const float* __restrict__ W0,
                                                   const float* __restrict__ W1,
                                                   const float* __restrict__ W2,
                                                   _Float16* __restrict__ Wt, int wtb,
                                                   const int* __restrict__ batch,
                                                   int* __restrict__ gstart, int n, int g) {
  int t = threadIdx.x;
  if (blockIdx.x >= hb + wtb) {
    // graph boundaries from sorted batch
    int i = (blockIdx.x - hb - wtb) * 256 + t;
    if (i >= n) return;
    int bi = batch[i];
    int bp = (i == 0) ? -1 : batch[i - 1];
    for (int q = bp + 1; q <= bi; ++q) gstart[q] = i;
    if (i == n - 1)
      for (int q = bi + 1; q <= g; ++q) gstart[q] = n;
    return;
  }
  if (blockIdx.x >= hb) {
    // Wt[l][n][k] = W_l[k][n]
    int i = (blockIdx.x - hb) * 256 + t;
    if (i < 3 * FEAT * FEAT) {
      int l = i / (FEAT * FEAT);
      int r = i - l * (FEAT * FEAT);
      int nn = r >> 7, kk = r & 127;
      const float* W = (l == 0) ? W0 : (l == 1) ? W1 : W2;
      Wt[i] = (_Float16)W[kk * FEAT + nn];
    }
    return;
  }
  __shared__ int lh[NB_MAX];
  for (int i = t; i < nb; i += 256) lh[i] = 0;
  __syncthreads();
  int r0 = blockIdx.x * epb;
  int r1 = min(r0 + epb, ne);
  for (int k = r0 + t; k < r1; k += 256) atomicAdd(&lh[ei[ne + k] >> 7], 1);
  __syncthreads();
  for (int i = t; i < nb; i += 256)
    if (lh[i]) atomicAdd(&bhist[i], lh[i]);
}

// ---- exclusive scan of bucket counts -> bstart (kept) and bcur (consumed) ----
__global__ void __launch_bounds__(512) bscan_kernel(const int* __restrict__ bhist,
                                                    int* __restrict__ bstart,
                                                    int* __restrict__ bcur,
                                                    int nb, int ne) {
  __shared__ int sh[512];
  int t = threadIdx.x;
  int v = (t < nb) ? bhist[t] : 0;
  sh[t] = v;
  __syncthreads();
  int x = v;
  for (int d = 1; d < 512; d <<= 1) {
    int y = (t >= d) ? sh[t - d] : 0;
    __syncthreads();
    x += y;
    sh[t] = x;
    __syncthreads();
  }
  if (t < nb) {
    bstart[t] = x - v;
    bcur[t] = x - v;
  }
  if (t == 0) bstart[nb] = ne;
}

// ---- pass 1: scatter packed (dst&127,src) into dst-buckets ----
__global__ void __launch_bounds__(256) scatter_kernel(const int* __restrict__ ei,
                                                      int* __restrict__ bcur,
                                                      unsigned* __restrict__ buf,
                                                      int ne, int nb, int epb) {
  __shared__ int lh[NB_MAX], lbs[NB_MAX];
  int t = threadIdx.x;
  for (int i = t; i < nb; i += 256) lh[i] = 0;
  __syncthreads();
  int r0 = blockIdx.x * epb;
  int r1 = min(r0 + epb, ne);
  for (int k = r0 + t; k < r1; k += 256) atomicAdd(&lh[ei[ne + k] >> 7], 1);
  __syncthreads();
  for (int i = t; i < nb; i += 256) {
    int c = lh[i];
    lbs[i] = c ? atomicAdd(&bcur[i], c) : 0;
    lh[i] = 0;  // reuse as local cursor
  }
  __syncthreads();
  for (int k = r0 + t; k < r1; k += 256) {
    int src = ei[k];
    int dst = ei[ne + k];
    int b = dst >> 7;
    int p = lbs[b] + atomicAdd(&lh[b], 1);
    buf[p] = (unsigned)src | ((unsigned)(dst & 127) << 25);
  }
}

// ---- pass 2: one block per bucket: count -> padded scan -> offend/dis/csr ----
// csr segments start 8-aligned, padded to multiple of 8 with sentinel index n.
__global__ void __launch_bounds__(256) bucket_build_kernel(const unsigned* __restrict__ buf,
                                                           const int* __restrict__ bstart,
                                                           int2* __restrict__ offend,
                                                           int* __restrict__ csr,
                                                           float* __restrict__ dis, int n) {
  __shared__ int cnt[128], cur[128], sh[128], ps[128];
  int b = blockIdx.x, t = threadIdx.x;
  int e0 = bstart[b], e1 = bstart[b + 1];
  int pb = ((e0 + 7) & ~7) + 1024 * b;  // padded 8-aligned bucket base
  if (t < 128) cnt[t] = 0;
  __syncthreads();
  for (int k = e0 + t; k < e1; k += 256) atomicAdd(&cnt[buf[k] >> 25], 1);
  __syncthreads();
  int v = 0, pdv = 0;
  if (t < 128) {
    v = cnt[t];
    pdv = (v + 7) & ~7;
    sh[t] = pdv;
  }
  __syncthreads();
  int x = pdv;
  for (int d = 1; d < 128; d <<= 1) {
    int y = (t < 128 && t >= d) ? sh[t - d] : 0;
    __syncthreads();
    if (t < 128) {
      x += y;
      sh[t] = x;
    }
    __syncthreads();
  }
  if (t < 128) {
    int node = (b << 7) + t;
    int st = x - pdv;  // local padded exclusive start
    ps[t] = st;
    cur[t] = st;
    if (node < n) {
      offend[node] = make_int2(pb + st, pb + st + v);
      dis[node] = rsqrtf((float)(v + 1));
    }
  }
  __syncthreads();
  for (int k = e0 + t; k < e1; k += 256) {
    unsigned u = buf[k];
    int d = u >> 25;
    int p = atomicAdd(&cur[d], 1);
    csr[pb + p] = (int)(u & 0x1FFFFFFu);
  }
  __syncthreads();
  // fill padding slots with sentinel (zero-row index n)
  if (t < 128) {
    int pd = (cnt[t] + 7) & ~7;
    for (int q = cnt[t]; q < pd; ++q) csr[pb + ps[t] + q] = n;
  }
}

// Hs(f16) = (X @ W) * dis[row] via v_mfma_f32_16x16x32_f16 (layer 0, f32 input)
__global__ void __launch_bounds__(256) gemm_mfma_kernel(const float* __restrict__ Xf,
                                                        const _Float16* __restrict__ Wt,
                                                        const float* __restrict__ dis,
                                                        _Float16* __restrict__ Hs, int n) {
  __shared__ _Float16 st[64 * FEAT];  // 16 KB epilogue staging
  int tid = threadIdx.x;
  int w = tid >> 6, lane = tid & 63;
  int l15 = lane & 15, hi = lane >> 4;

  int rowA = blockIdx.x * 64 + w * 16 + l15;
  int rA = min(rowA, n - 1);

  f4 acc[8];
#pragma unroll
  for (int nb = 0; nb < 8; ++nb) acc[nb] = (f4)(0.f);

#pragma unroll
  for (int kk = 0; kk < FEAT; kk += 32) {
    int ko = kk + hi * 8;
    h8 a;
    float4 x0 = *(const float4*)&Xf[(size_t)rA * FEAT + ko];
    float4 x1 = *(const float4*)&Xf[(size_t)rA * FEAT + ko + 4];
    a[0] = (_Float16)x0.x; a[1] = (_Float16)x0.y; a[2] = (_Float16)x0.z; a[3] = (_Float16)x0.w;
    a[4] = (_Float16)x1.x; a[5] = (_Float16)x1.y; a[6] = (_Float16)x1.z; a[7] = (_Float16)x1.w;
#pragma unroll
    for (int nb = 0; nb < 8; ++nb) {
      h8 bfr = *(const h8*)&Wt[(nb * 16 + l15) * FEAT + ko];
      acc[nb] = __builtin_amdgcn_mfma_f32_16x16x32_f16(a, bfr, acc[nb], 0, 0, 0);
    }
  }

  float dv[4];
#pragma unroll
  for (int r = 0; r < 4; ++r) {
    int grow = blockIdx.x * 64 + w * 16 + hi * 4 + r;
    dv[r] = dis[min(grow, n - 1)];
  }
#pragma unroll
  for (int nb = 0; nb < 8; ++nb)
#pragma unroll
    for (int r = 0; r < 4; ++r)
      st[(w * 16 + hi * 4 + r) * FEAT + nb * 16 + l15] = (_Float16)(acc[nb][r] * dv[r]);
  __syncthreads();

  int rowbase = blockIdx.x * 64;
#pragma unroll
  for (int i = tid; i < 64 * FEAT / 8; i += 256) {
    int row = rowbase + (i >> 4);
    if (row < n)
      *(uint4*)&Hs[(size_t)row * FEAT + (i & 15) * 8] =
          *(const uint4*)&st[(i >> 4) * FEAT + (i & 15) * 8];
  }
}

// Fused: A = relu(dis*agg(Hs_in) + b_prev) per node (64 nodes -> swizzled LDS
// tile), then Hs_out = (A @ W) * dis via MFMA. 256 thr / 4 waves / 64 rows.
__global__ void __launch_bounds__(256) fused_kernel(const h8* __restrict__ Hs_in,
                                                    const int* __restrict__ csr,
                                                    const int2* __restrict__ offend,
                                                    const float* __restrict__ dis,
                                                    const float* __restrict__ bias,
                                                    const _Float16* __restrict__ Wt,
                                                    _Float16* __restrict__ Hs_out, int n) {
  __shared__ char xsb[64 * 256];  // 16 KB: A-tile, then reused as epilogue staging
  int tid = threadIdx.x;
  int w = tid >> 6, lane = tid & 63;
  int grp = lane >> 4, lig = lane & 15;
  int row0 = blockIdx.x * 64;
  int g16 = w * 4 + grp;  // 0..15: group id in block

  float4 b0 = ((const float4*)bias)[lig * 2];
  float4 b1 = ((const float4*)bias)[lig * 2 + 1];
  float bb[8] = {b0.x, b0.y, b0.z, b0.w, b1.x, b1.y, b1.z, b1.w};

  // ---- phase 1: aggregate 4 nodes per 16-lane group (branchless padded) ----
  for (int m = 0; m < 4; ++m) {
    int ar = g16 * 4 + m;
    int nd = min(row0 + ar, n - 1);
    int2 oe = offend[nd];
    float a0[8], a1[8];
    h8 v = Hs_in[(size_t)nd * 16 + lig];  // self-loop term
#pragma unroll
    for (int j = 0; j < 8; ++j) {
      a0[j] = (float)v[j];
      a1[j] = 0.f;
    }
    gather_pad8(Hs_in, csr, oe.x, oe.y, lig, a0, a1);
    float d = dis[nd];
    h8 o;
#pragma unroll
    for (int j = 0; j < 8; ++j)
      o[j] = (_Float16)fmaxf(fmaf(d, a0[j] + a1[j], bb[j]), 0.f);
    *(h8*)(xsb + swz(ar, lig * 16)) = o;
  }
  __syncthreads();

  // ---- phase 2: MFMA from LDS A-tile ----
  int l15 = lane & 15, hi = lane >> 4;
  f4 acc[8];
#pragma unroll
  for (int nb = 0; nb < 8; ++nb) acc[nb] = (f4)(0.f);
#pragma unroll
  for (int kk = 0; kk < FEAT; kk += 32) {
    int ko = kk + hi * 8;
    h8 a = *(const h8*)(xsb + swz(w * 16 + l15, ko * 2));
#pragma unroll
    for (int nb = 0; nb < 8; ++nb) {
      h8 bfr = *(const h8*)&Wt[(nb * 16 + l15) * FEAT + ko];
      acc[nb] = __builtin_amdgcn_mfma_f32_16x16x32_f16(a, bfr, acc[nb], 0, 0, 0);
    }
  }

  float dv[4];
#pragma unroll
  for (int r = 0; r < 4; ++r) {
    int grow = row0 + w * 16 + hi * 4 + r;
    dv[r] = dis[min(grow, n - 1)];
  }
  __syncthreads();  // all A-reads done before reusing xsb as staging
#pragma unroll
  for (int nb = 0; nb < 8; ++nb)
#pragma unroll
    for (int r = 0; r < 4; ++r) {
      int srow = w * 16 + hi * 4 + r;
      *(_Float16*)(xsb + swz(srow, (nb * 16 + l15) * 2)) = (_Float16)(acc[nb][r] * dv[r]);
    }
  __syncthreads();
#pragma unroll
  for (int i = tid; i < 64 * FEAT / 8; i += 256) {
    int row = row0 + (i >> 4);
    if (row < n)
      *(uint4*)&Hs_out[(size_t)row * FEAT + (i & 15) * 8] =
          *(const uint4*)(xsb + swz(i >> 4, (i & 15) * 16));
  }
}

// Layer-2 agg standalone: same group structure as fused phase 1, writes h8 rows.
__global__ void __launch_bounds__(256) agg_kernel(const h8* __restrict__ Hs,
                                                  const int* __restrict__ csr,
                                                  const int2* __restrict__ offend,
                                                  const float* __restrict__ dis,
                                                  const float* __restrict__ bias,
                                                  h8* __restrict__ out, int n) {
  int tid = threadIdx.x;
  int g16 = tid >> 4, lig = tid & 15;  // 16 groups x 16 lanes
  int row0 = blockIdx.x * 64;

  float4 b0 = ((const float4*)bias)[lig * 2];
  float4 b1 = ((const float4*)bias)[lig * 2 + 1];
  float bb[8] = {b0.x, b0.y, b0.z, b0.w, b1.x, b1.y, b1.z, b1.w};

  for (int m = 0; m < 4; ++m) {
    int node = row0 + g16 * 4 + m;
    if (node >= n) return;
    int2 oe = offend[node];
    float a0[8], a1[8];
    h8 v = Hs[(size_t)node * 16 + lig];  // self-loop term
#pragma unroll
    for (int j = 0; j < 8; ++j) {
      a0[j] = (float)v[j];
      a1[j] = 0.f;
    }
    gather_pad8(Hs, csr, oe.x, oe.y, lig, a0, a1);
    float d = dis[node];
    h8 o;
#pragma unroll
    for (int j = 0; j < 8; ++j)
      o[j] = (_Float16)fmaxf(fmaf(d, a0[j] + a1[j], bb[j]), 0.f);
    out[(size_t)node * 16 + lig] = o;
  }
}

// mean-pool per graph (f16 input) + linear(128->10) + log_softmax
__global__ void __launch_bounds__(128) pool_kernel(const __half* __restrict__ h,
                                                   const int* __restrict__ gstart,
                                                   const float* __restrict__ lw,
                                                   const float* __restrict__ lb,
                                                   float* __restrict__ out) {
  int g = blockIdx.x;
  int t = threadIdx.x;
  int s = gstart[g];
  int e = gstart[g + 1];
  float a0 = 0.f, a1 = 0.f, a2 = 0.f, a3 = 0.f;
  int i = s;
  for (; i + 4 <= e; i += 4) {
    a0 += __half2float(h[(size_t)i * FEAT + t]);
    a1 += __half2float(h[(size_t)(i + 1) * FEAT + t]);
    a2 += __half2float(h[(size_t)(i + 2) * FEAT + t]);
    a3 += __half2float(h[(size_t)(i + 3) * FEAT + t]);
  }
  for (; i < e; ++i) a0 += __half2float(h[(size_t)i * FEAT + t]);
  float acc = a0 + a1 + a2 + a3;
  float cnt = (float)(e - s);
  float pooled = acc / fmaxf(cnt, 1.f);
  __shared__ float lds[FEAT];
  __shared__ float logits[NCLASS];
  lds[t] = pooled;
  __syncthreads();
  if (t < NCLASS) {
    float z = lb[t];
    for (int k = 0; k < FEAT; ++k) z += lds[k] * lw[k * NCLASS + t];
    logits[t] = z;
  }
  __syncthreads();
  if (t < NCLASS) {
    float m = logits[0];
#pragma unroll
    for (int c = 1; c < NCLASS; ++c) m = fmaxf(m, logits[c]);
    float ssum = 0.f;
#pragma unroll
    for (int c = 0; c < NCLASS; ++c) ssum += expf(logits[c] - m);
    out[(size_t)g * NCLASS + t] = logits[t] - m - logf(ssum);
  }
}

extern "C" void kernel_launch(void* const* d_in, const int* in_sizes, int n_in,
                              void* d_out, int out_size, void* d_ws, size_t ws_size,
                              hipStream_t stream) {
  const float* x = (const float*)d_in[0];
  const int* ei = (const int*)d_in[1];
  const int* batch = (const int*)d_in[2];
  const float* W0 = (const float*)d_in[3];
  const float* b0 = (const float*)d_in[4];
  const float* W1 = (const float*)d_in[5];
  const float* b1 = (const float*)d_in[6];
  const float* W2 = (const float*)d_in[7];
  const float* b2 = (const float*)d_in[8];
  const float* lw = (const float*)d_in[9];
  const float* lb = (const float*)d_in[10];

  int n = in_sizes[2];        // 50000 nodes
  int ne = in_sizes[1] / 2;   // 800000 edges
  int g = out_size / NCLASS;  // 512 graphs
  int nb = (n + 127) >> 7;    // dst buckets (391)
  int hblocks = 120;
  int epb = (ne + hblocks - 1) / hblocks;
  int wtblocks = (3 * FEAT * FEAT + 255) / 256;  // 192
  int bndblocks = (n + 255) / 256;

  char* ws = (char*)d_ws;
  size_t p = 0;
  auto alloc = [&](size_t bytes) {
    size_t cur = p;
    p += (bytes + 255) & ~(size_t)255;
    return cur;
  };
  int2* offend = (int2*)(ws + alloc((size_t)n * 8));
  int* csr = (int*)(ws + alloc(((size_t)ne + 1024 * nb + 64) * 4));
  int* bhist = (int*)(ws + alloc((size_t)NB_MAX * 4));
  int* bstart = (int*)(ws + alloc((size_t)(NB_MAX + 1) * 4));
  int* bcur = (int*)(ws + alloc((size_t)NB_MAX * 4));
  int* gstart = (int*)(ws + alloc((size_t)(g + 1) * 4));
  float* dis = (float*)(ws + alloc((size_t)n * 4));
  unsigned* buf = (unsigned*)(ws + alloc((size_t)ne * 4));
  _Float16* Wt = (_Float16*)(ws + alloc((size_t)3 * FEAT * FEAT * 2));
  _Float16* HA = (_Float16*)(ws + alloc((size_t)(n + 1) * FEAT * 2));  // +1 zero row
  _Float16* HB = (_Float16*)(ws + alloc((size_t)(n + 1) * FEAT * 2));

  hipMemsetAsync(bhist, 0, NB_MAX * 4, stream);
  hipMemsetAsync(HA + (size_t)n * FEAT, 0, FEAT * 2, stream);  // sentinel zero rows
  hipMemsetAsync(HB + (size_t)n * FEAT, 0, FEAT * 2, stream);

  prep_kernel<<<hblocks + wtblocks + bndblocks, 256, 0, stream>>>(
      ei, bhist, ne, nb, epb, hblocks, W0, W1, W2, Wt, wtblocks, batch, gstart, n, g);
  bscan_kernel<<<1, 512, 0, stream>>>(bhist, bstart, bcur, nb, ne);
  scatter_kernel<<<hblocks, 256, 0, stream>>>(ei, bcur, buf, ne, nb, epb);
  bucket_build_kernel<<<nb, 256, 0, stream>>>(buf, bstart, offend, csr, dis, n);

  int gblocks = (n + 63) / 64;
  // layer 0: X(f32) @ W0 * dis -> HA
  gemm_mfma_kernel<<<gblocks, 256, 0, stream>>>(x, Wt, dis, HA, n);
  // layer 0 agg + layer 1 gemm: HA -> HB
  fused_kernel<<<gblocks, 256, 0, stream>>>((const h8*)HA, csr, offend, dis, b0,
                                            Wt + (size_t)1 * FEAT * FEAT, HB, n);
  // layer 1 agg + layer 2 gemm: HB -> HA
  fused_kernel<<<gblocks, 256, 0, stream>>>((const h8*)HB, csr, offend, dis, b1,
                                            Wt + (size_t)2 * FEAT * FEAT, HA, n);
  // layer 2 agg: HA -> HB (pool input)
  agg_kernel<<<gblocks, 256, 0, stream>>>((const h8*)HA, csr, offend, dis, b2, (h8*)HB, n);

  pool_kernel<<<g, 128, 0, stream>>>((const __half*)HB, gstart, lw, lb, (float*)d_out);
}

// Round 11
// 221.855 us; speedup vs baseline: 1.0744x; 1.0159x over previous
//
#include <hip/hip_runtime.h>
#include <hip/hip_fp16.h>

// GCN forward: 3x (MFMA GEMM + normalized adjacency aggregate + ReLU) + mean-pool + linear + log_softmax
// N=50000, E=800000, F=H=128, C=10, G=512
// Round 11: occupancy was grid-capped (782 blocks x 4 waves = 12 waves/CU = 38%).
// Fused + agg re-tiled to 512-thr/8-wave blocks over the same 64-row tile ->
// 24 waves/CU ceiling. Gather = branchless padded 4-deep (VGPR <= ~64).

#define FEAT 128
#define NCLASS 10
#define NB_MAX 512  // max dst buckets (n <= 65536 here: 391)

typedef _Float16 h8 __attribute__((ext_vector_type(8)));
typedef float f4 __attribute__((ext_vector_type(4)));

// LDS tile swizzle: row stride 256B; XOR row&7 into byte bits 4..6.
__device__ inline int swz(int row, int cbyte) { return row * 256 + (cbyte ^ ((row & 7) << 4)); }

// Branchless padded gather, 4 loads in flight: [s, s+pad8(e-s)) with sentinel
// entries = n (zero row). s is 8-aligned.
__device__ inline void gather_pad4(const h8* __restrict__ Hs, const int* __restrict__ csr,
                                   int s, int e, int lig, float* a0, float* a1) {
  int ep = s + ((e - s + 7) & ~7);
  for (int k = s; k < ep; k += 4) {
    int4 c = *(const int4*)&csr[k];
    h8 v0 = Hs[(size_t)c.x * 16 + lig];
    h8 v1 = Hs[(size_t)c.y * 16 + lig];
    h8 v2 = Hs[(size_t)c.z * 16 + lig];
    h8 v3 = Hs[(size_t)c.w * 16 + lig];
#pragma unroll
    for (int j = 0; j < 8; ++j) a0[j] += (float)v0[j];
#pragma unroll
    for (int j = 0; j < 8; ++j) a1[j] += (float)v1[j];
#pragma unroll
    for (int j = 0; j < 8; ++j) a0[j] += (float)v2[j];
#pragma unroll
    for (int j = 0; j < 8; ++j) a1[j] += (float)v3[j];
  }
}

// ---- pass 0 combined: bucket histogram (blocks <hb) + Wt convert + bounds ----
__global__ void __launch_bounds__(256) prep_kernel(const int* __restrict__ ei,
                                                   int* __restrict__ bhist,
                                                   int ne, int nb, int epb, int hb,
                                                   const float* __restrict__ W0,
                                                   const float* __restrict__ W1,
                                                   const float* __restrict__ W2,
                                                   _Float16* __restrict__ Wt, int wtb,
                                                   const int* __restrict__ batch,
                                                   int* __restrict__ gstart, int n, int g) {
  int t = threadIdx.x;
  if (blockIdx.x >= hb + wtb) {
    // graph boundaries from sorted batch
    int i = (blockIdx.x - hb - wtb) * 256 + t;
    if (i >= n) return;
    int bi = batch[i];
    int bp = (i == 0) ? -1 : batch[i - 1];
    for (int q = bp + 1; q <= bi; ++q) gstart[q] = i;
    if (i == n - 1)
      for (int q = bi + 1; q <= g; ++q) gstart[q] = n;
    return;
  }
  if (blockIdx.x >= hb) {
    // Wt[l][n][k] = W_l[k][n]
    int i = (blockIdx.x - hb) * 256 + t;
    if (i < 3 * FEAT * FEAT) {
      int l = i / (FEAT * FEAT);
      int r = i - l * (FEAT * FEAT);
      int nn = r >> 7, kk = r & 127;
      const float* W = (l == 0) ? W0 : (l == 1) ? W1 : W2;
      Wt[i] = (_Float16)W[kk * FEAT + nn];
    }
    return;
  }
  __shared__ int lh[NB_MAX];
  for (int i = t; i < nb; i += 256) lh[i] = 0;
  __syncthreads();
  int r0 = blockIdx.x * epb;
  int r1 = min(r0 + epb, ne);
  for (int k = r0 + t; k < r1; k += 256) atomicAdd(&lh[ei[ne + k] >> 7], 1);
  __syncthreads();
  for (int i = t; i < nb; i += 256)
    if (lh[i]) atomicAdd(&bhist[i], lh[i]);
}

// ---- exclusive scan of bucket counts -> bstart (kept) and bcur (consumed) ----
__global__ void __launch_bounds__(512) bscan_kernel(const int* __restrict__ bhist,
                                                    int* __restrict__ bstart,
                                                    int* __restrict__ bcur,
                                                    int nb, int ne) {
  __shared__ int sh[512];
  int t = threadIdx.x;
  int v = (t < nb) ? bhist[t] : 0;
  sh[t] = v;
  __syncthreads();
  int x = v;
  for (int d = 1; d < 512; d <<= 1) {
    int y = (t >= d) ? sh[t - d] : 0;
    __syncthreads();
    x += y;
    sh[t] = x;
    __syncthreads();
  }
  if (t < nb) {
    bstart[t] = x - v;
    bcur[t] = x - v;
  }
  if (t == 0) bstart[nb] = ne;
}

// ---- pass 1: scatter packed (dst&127,src) into dst-buckets ----
__global__ void __launch_bounds__(256) scatter_kernel(const int* __restrict__ ei,
                                                      int* __restrict__ bcur,
                                                      unsigned* __restrict__ buf,
                                                      int ne, int nb, int epb) {
  __shared__ int lh[NB_MAX], lbs[NB_MAX];
  int t = threadIdx.x;
  for (int i = t; i < nb; i += 256) lh[i] = 0;
  __syncthreads();
  int r0 = blockIdx.x * epb;
  int r1 = min(r0 + epb, ne);
  for (int k = r0 + t; k < r1; k += 256) atomicAdd(&lh[ei[ne + k] >> 7], 1);
  __syncthreads();
  for (int i = t; i < nb; i += 256) {
    int c = lh[i];
    lbs[i] = c ? atomicAdd(&bcur[i], c) : 0;
    lh[i] = 0;  // reuse as local cursor
  }
  __syncthreads();
  for (int k = r0 + t; k < r1; k += 256) {
    int src = ei[k];
    int dst = ei[ne + k];
    int b = dst >> 7;
    int p = lbs[b] + atomicAdd(&lh[b], 1);
    buf[p] = (unsigned)src | ((unsigned)(dst & 127) << 25);
  }
}

// ---- pass 2: one block per bucket: count -> padded scan -> offend/dis/csr ----
// csr segments start 8-aligned, padded to multiple of 8 with sentinel index n.
__global__ void __launch_bounds__(256) bucket_build_kernel(const unsigned* __restrict__ buf,
                                                           const int* __restrict__ bstart,
                                                           int2* __restrict__ offend,
                                                           int* __restrict__ csr,
                                                           float* __restrict__ dis, int n) {
  __shared__ int cnt[128], cur[128], sh[128], ps[128];
  int b = blockIdx.x, t = threadIdx.x;
  int e0 = bstart[b], e1 = bstart[b + 1];
  int pb = ((e0 + 7) & ~7) + 1024 * b;  // padded 8-aligned bucket base
  if (t < 128) cnt[t] = 0;
  __syncthreads();
  for (int k = e0 + t; k < e1; k += 256) atomicAdd(&cnt[buf[k] >> 25], 1);
  __syncthreads();
  int v = 0, pdv = 0;
  if (t < 128) {
    v = cnt[t];
    pdv = (v + 7) & ~7;
    sh[t] = pdv;
  }
  __syncthreads();
  int x = pdv;
  for (int d = 1; d < 128; d <<= 1) {
    int y = (t < 128 && t >= d) ? sh[t - d] : 0;
    __syncthreads();
    if (t < 128) {
      x += y;
      sh[t] = x;
    }
    __syncthreads();
  }
  if (t < 128) {
    int node = (b << 7) + t;
    int st = x - pdv;  // local padded exclusive start
    ps[t] = st;
    cur[t] = st;
    if (node < n) {
      offend[node] = make_int2(pb + st, pb + st + v);
      dis[node] = rsqrtf((float)(v + 1));
    }
  }
  __syncthreads();
  for (int k = e0 + t; k < e1; k += 256) {
    unsigned u = buf[k];
    int d = u >> 25;
    int p = atomicAdd(&cur[d], 1);
    csr[pb + p] = (int)(u & 0x1FFFFFFu);
  }
  __syncthreads();
  // fill padding slots with sentinel (zero-row index n)
  if (t < 128) {
    int pd = (cnt[t] + 7) & ~7;
    for (int q = cnt[t]; q < pd; ++q) csr[pb + ps[t] + q] = n;
  }
}

// Hs(f16) = (X @ W) * dis[row] via v_mfma_f32_16x16x32_f16 (layer 0, f32 input)
__global__ void __launch_bounds__(256) gemm_mfma_kernel(const float* __restrict__ Xf,
                                                        const _Float16* __restrict__ Wt,
                                                        const float* __restrict__ dis,
                                                        _Float16* __restrict__ Hs, int n) {
  __shared__ _Float16 st[64 * FEAT];  // 16 KB epilogue staging
  int tid = threadIdx.x;
  int w = tid >> 6, lane = tid & 63;
  int l15 = lane & 15, hi = lane >> 4;

  int rowA = blockIdx.x * 64 + w * 16 + l15;
  int rA = min(rowA, n - 1);

  f4 acc[8];
#pragma unroll
  for (int nb = 0; nb < 8; ++nb) acc[nb] = (f4)(0.f);

#pragma unroll
  for (int kk = 0; kk < FEAT; kk += 32) {
    int ko = kk + hi * 8;
    h8 a;
    float4 x0 = *(const float4*)&Xf[(size_t)rA * FEAT + ko];
    float4 x1 = *(const float4*)&Xf[(size_t)rA * FEAT + ko + 4];
    a[0] = (_Float16)x0.x; a[1] = (_Float16)x0.y; a[2] = (_Float16)x0.z; a[3] = (_Float16)x0.w;
    a[4] = (_Float16)x1.x; a[5] = (_Float16)x1.y; a[6] = (_Float16)x1.z; a[7] = (_Float16)x1.w;
#pragma unroll
    for (int nb = 0; nb < 8; ++nb) {
      h8 bfr = *(const h8*)&Wt[(nb * 16 + l15) * FEAT + ko];
      acc[nb] = __builtin_amdgcn_mfma_f32_16x16x32_f16(a, bfr, acc[nb], 0, 0, 0);
    }
  }

  float dv[4];
#pragma unroll
  for (int r = 0; r < 4; ++r) {
    int grow = blockIdx.x * 64 + w * 16 + hi * 4 + r;
    dv[r] = dis[min(grow, n - 1)];
  }
#pragma unroll
  for (int nb = 0; nb < 8; ++nb)
#pragma unroll
    for (int r = 0; r < 4; ++r)
      st[(w * 16 + hi * 4 + r) * FEAT + nb * 16 + l15] = (_Float16)(acc[nb][r] * dv[r]);
  __syncthreads();

  int rowbase = blockIdx.x * 64;
#pragma unroll
  for (int i = tid; i < 64 * FEAT / 8; i += 256) {
    int row = rowbase + (i >> 4);
    if (row < n)
      *(uint4*)&Hs[(size_t)row * FEAT + (i & 15) * 8] =
          *(const uint4*)&st[(i >> 4) * FEAT + (i & 15) * 8];
  }
}

// Fused: A = relu(dis*agg(Hs_in) + b_prev) per node (64 nodes -> swizzled LDS
// tile), then Hs_out = (A @ W) * dis via MFMA.
// 512 thr / 8 waves / 64 rows: phase 1 = 32 groups x 2 nodes (4-deep gather);
// phase 2 = wave (strip = w&3, colhalf = w>>2) computes 16 rows x 64 cols.
__global__ void __launch_bounds__(512, 6) fused_kernel(const h8* __restrict__ Hs_in,
                                                       const int* __restrict__ csr,
                                                       const int2* __restrict__ offend,
                                                       const float* __restrict__ dis,
                                                       const float* __restrict__ bias,
                                                       const _Float16* __restrict__ Wt,
                                                       _Float16* __restrict__ Hs_out, int n) {
  __shared__ char xsb[64 * 256];  // 16 KB: A-tile, then reused as epilogue staging
  int tid = threadIdx.x;
  int w = tid >> 6, lane = tid & 63;
  int grp = lane >> 4, lig = lane & 15;
  int row0 = blockIdx.x * 64;
  int g32 = w * 4 + grp;  // 0..31: group id in block

  float4 b0 = ((const float4*)bias)[lig * 2];
  float4 b1 = ((const float4*)bias)[lig * 2 + 1];
  float bb[8] = {b0.x, b0.y, b0.z, b0.w, b1.x, b1.y, b1.z, b1.w};

  // ---- phase 1: aggregate 2 nodes per 16-lane group (branchless padded) ----
#pragma unroll
  for (int m = 0; m < 2; ++m) {
    int ar = g32 * 2 + m;
    int nd = min(row0 + ar, n - 1);
    int2 oe = offend[nd];
    float a0[8], a1[8];
    h8 v = Hs_in[(size_t)nd * 16 + lig];  // self-loop term
#pragma unroll
    for (int j = 0; j < 8; ++j) {
      a0[j] = (float)v[j];
      a1[j] = 0.f;
    }
    gather_pad4(Hs_in, csr, oe.x, oe.y, lig, a0, a1);
    float d = dis[nd];
    h8 o;
#pragma unroll
    for (int j = 0; j < 8; ++j)
      o[j] = (_Float16)fmaxf(fmaf(d, a0[j] + a1[j], bb[j]), 0.f);
    *(h8*)(xsb + swz(ar, lig * 16)) = o;
  }
  __syncthreads();

  // ---- phase 2: MFMA from LDS A-tile; wave = (strip, colhalf) ----
  int l15 = lane & 15, hi = lane >> 4;
  int strip = w & 3, ch = w >> 2;
  f4 acc[4];
#pragma unroll
  for (int nb = 0; nb < 4; ++nb) acc[nb] = (f4)(0.f);
#pragma unroll
  for (int kk = 0; kk < FEAT; kk += 32) {
    int ko = kk + hi * 8;
    h8 a = *(const h8*)(xsb + swz(strip * 16 + l15, ko * 2));
#pragma unroll
    for (int nb = 0; nb < 4; ++nb) {
      h8 bfr = *(const h8*)&Wt[(ch * 64 + nb * 16 + l15) * FEAT + ko];
      acc[nb] = __builtin_amdgcn_mfma_f32_16x16x32_f16(a, bfr, acc[nb], 0, 0, 0);
    }
  }

  float dv[4];
#pragma unroll
  for (int r = 0; r < 4; ++r) {
    int grow = row0 + strip * 16 + hi * 4 + r;
    dv[r] = dis[min(grow, n - 1)];
  }
  __syncthreads();  // all A-reads done before reusing xsb as staging
#pragma unroll
  for (int nb = 0; nb < 4; ++nb)
#pragma unroll
    for (int r = 0; r < 4; ++r) {
      int srow = strip * 16 + hi * 4 + r;
      *(_Float16*)(xsb + swz(srow, (ch * 64 + nb * 16 + l15) * 2)) =
          (_Float16)(acc[nb][r] * dv[r]);
    }
  __syncthreads();
#pragma unroll
  for (int i = tid; i < 64 * FEAT / 8; i += 512) {
    int row = row0 + (i >> 4);
    if (row < n)
      *(uint4*)&Hs_out[(size_t)row * FEAT + (i & 15) * 8] =
          *(const uint4*)(xsb + swz(i >> 4, (i & 15) * 16));
  }
}

// Layer-2 agg standalone: 512 thr, 32 groups x 2 nodes, writes h8 rows.
__global__ void __launch_bounds__(512, 6) agg_kernel(const h8* __restrict__ Hs,
                                                     const int* __restrict__ csr,
                                                     const int2* __restrict__ offend,
                                                     const float* __restrict__ dis,
                                                     const float* __restrict__ bias,
                                                     h8* __restrict__ out, int n) {
  int tid = threadIdx.x;
  int g32 = tid >> 4, lig = tid & 15;  // 32 groups x 16 lanes
  int row0 = blockIdx.x * 64;

  float4 b0 = ((const float4*)bias)[lig * 2];
  float4 b1 = ((const float4*)bias)[lig * 2 + 1];
  float bb[8] = {b0.x, b0.y, b0.z, b0.w, b1.x, b1.y, b1.z, b1.w};

#pragma unroll
  for (int m = 0; m < 2; ++m) {
    int node = row0 + g32 * 2 + m;
    if (node < n) {
      int2 oe = offend[node];
      float a0[8], a1[8];
      h8 v = Hs[(size_t)node * 16 + lig];  // self-loop term
#pragma unroll
      for (int j = 0; j < 8; ++j) {
        a0[j] = (float)v[j];
        a1[j] = 0.f;
      }
      gather_pad4(Hs, csr, oe.x, oe.y, lig, a0, a1);
      float d = dis[node];
      h8 o;
#pragma unroll
      for (int j = 0; j < 8; ++j)
        o[j] = (_Float16)fmaxf(fmaf(d, a0[j] + a1[j], bb[j]), 0.f);
      out[(size_t)node * 16 + lig] = o;
    }
  }
}

// mean-pool per graph (f16 input) + linear(128->10) + log_softmax
__global__ void __launch_bounds__(128) pool_kernel(const __half* __restrict__ h,
                                                   const int* __restrict__ gstart,
                                                   const float* __restrict__ lw,
                                                   const float* __restrict__ lb,
                                                   float* __restrict__ out) {
  int g = blockIdx.x;
  int t = threadIdx.x;
  int s = gstart[g];
  int e = gstart[g + 1];
  float a0 = 0.f, a1 = 0.f, a2 = 0.f, a3 = 0.f;
  int i = s;
  for (; i + 4 <= e; i += 4) {
    a0 += __half2float(h[(size_t)i * FEAT + t]);
    a1 += __half2float(h[(size_t)(i + 1) * FEAT + t]);
    a2 += __half2float(h[(size_t)(i + 2) * FEAT + t]);
    a3 += __half2float(h[(size_t)(i + 3) * FEAT + t]);
  }
  for (; i < e; ++i) a0 += __half2float(h[(size_t)i * FEAT + t]);
  float acc = a0 + a1 + a2 + a3;
  float cnt = (float)(e - s);
  float pooled = acc / fmaxf(cnt, 1.f);
  __shared__ float lds[FEAT];
  __shared__ float logits[NCLASS];
  lds[t] = pooled;
  __syncthreads();
  if (t < NCLASS) {
    float z = lb[t];
    for (int k = 0; k < FEAT; ++k) z += lds[k] * lw[k * NCLASS + t];
    logits[t] = z;
  }
  __syncthreads();
  if (t < NCLASS) {
    float m = logits[0];
#pragma unroll
    for (int c = 1; c < NCLASS; ++c) m = fmaxf(m, logits[c]);
    float ssum = 0.f;
#pragma unroll
    for (int c = 0; c < NCLASS; ++c) ssum += expf(logits[c] - m);
    out[(size_t)g * NCLASS + t] = logits[t] - m - logf(ssum);
  }
}

extern "C" void kernel_launch(void* const* d_in, const int* in_sizes, int n_in,
                              void* d_out, int out_size, void* d_ws, size_t ws_size,
                              hipStream_t stream) {
  const float* x = (const float*)d_in[0];
  const int* ei = (const int*)d_in[1];
  const int* batch = (const int*)d_in[2];
  const float* W0 = (const float*)d_in[3];
  const float* b0 = (const float*)d_in[4];
  const float* W1 = (const float*)d_in[5];
  const float* b1 = (const float*)d_in[6];
  const float* W2 = (const float*)d_in[7];
  const float* b2 = (const float*)d_in[8];
  const float* lw = (const float*)d_in[9];
  const float* lb = (const float*)d_in[10];

  int n = in_sizes[2];        // 50000 nodes
  int ne = in_sizes[1] / 2;   // 800000 edges
  int g = out_size / NCLASS;  // 512 graphs
  int nb = (n + 127) >> 7;    // dst buckets (391)
  int hblocks = 120;
  int epb = (ne + hblocks - 1) / hblocks;
  int wtblocks = (3 * FEAT * FEAT + 255) / 256;  // 192
  int bndblocks = (n + 255) / 256;

  char* ws = (char*)d_ws;
  size_t p = 0;
  auto alloc = [&](size_t bytes) {
    size_t cur = p;
    p += (bytes + 255) & ~(size_t)255;
    return cur;
  };
  int2* offend = (int2*)(ws + alloc((size_t)n * 8));
  int* csr = (int*)(ws + alloc(((size_t)ne + 1024 * nb + 64) * 4));
  int* bhist = (int*)(ws + alloc((size_t)NB_MAX * 4));
  int* bstart = (int*)(ws + alloc((size_t)(NB_MAX + 1) * 4));
  int* bcur = (int*)(ws + alloc((size_t)NB_MAX * 4));
  int* gstart = (int*)(ws + alloc((size_t)(g + 1) * 4));
  float* dis = (float*)(ws + alloc((size_t)n * 4));
  unsigned* buf = (unsigned*)(ws + alloc((size_t)ne * 4));
  _Float16* Wt = (_Float16*)(ws + alloc((size_t)3 * FEAT * FEAT * 2));
  _Float16* HA = (_Float16*)(ws + alloc((size_t)(n + 1) * FEAT * 2));  // +1 zero row
  _Float16* HB = (_Float16*)(ws + alloc((size_t)(n + 1) * FEAT * 2));

  hipMemsetAsync(bhist, 0, NB_MAX * 4, stream);
  hipMemsetAsync(HA + (size_t)n * FEAT, 0, FEAT * 2, stream);  // sentinel zero rows
  hipMemsetAsync(HB + (size_t)n * FEAT, 0, FEAT * 2, stream);

  prep_kernel<<<hblocks + wtblocks + bndblocks, 256, 0, stream>>>(
      ei, bhist, ne, nb, epb, hblocks, W0, W1, W2, Wt, wtblocks, batch, gstart, n, g);
  bscan_kernel<<<1, 512, 0, stream>>>(bhist, bstart, bcur, nb, ne);
  scatter_kernel<<<hblocks, 256, 0, stream>>>(ei, bcur, buf, ne, nb, epb);
  bucket_build_kernel<<<nb, 256, 0, stream>>>(buf, bstart, offend, csr, dis, n);

  int gblocks = (n + 63) / 64;
  // layer 0: X(f32) @ W0 * dis -> HA
  gemm_mfma_kernel<<<gblocks, 256, 0, stream>>>(x, Wt, dis, HA, n);
  // layer 0 agg + layer 1 gemm: HA -> HB
  fused_kernel<<<gblocks, 512, 0, stream>>>((const h8*)HA, csr, offend, dis, b0,
                                            Wt + (size_t)1 * FEAT * FEAT, HB, n);
  // layer 1 agg + layer 2 gemm: HB -> HA
  fused_kernel<<<gblocks, 512, 0, stream>>>((const h8*)HB, csr, offend, dis, b1,
                                            Wt + (size_t)2 * FEAT * FEAT, HA, n);
  // layer 2 agg: HA -> HB (pool input)
  agg_kernel<<<gblocks, 512, 0, stream>>>((const h8*)HA, csr, offend, dis, b2, (h8*)HB, n);

  pool_kernel<<<g, 128, 0, stream>>>((const __half*)HB, gstart, lw, lb, (float*)d_out);
}